// Round 4
// baseline (246.765 us; speedup 1.0000x reference)
//
#include <hip/hip_runtime.h>

#define RES   256
#define NCH   128   // C*F
#define NC    16
#define QG    32    // channels per transpose block
#define NPK   64    // packed uint32 per (p,y,x) position = NCH/2
#define NBINS 4096  // 16^3 Morton cells
#define TBLK  3072  // transpose grid size (4*256*3)

__device__ __forceinline__ unsigned int f32_to_bf16_rne(float f) {
    unsigned int u = __float_as_uint(f);
    return (u + 0x7FFFu + ((u >> 16) & 1u)) >> 16;
}
__device__ __forceinline__ float bf16_lo(unsigned int w) {
    return __uint_as_float(w << 16);
}
__device__ __forceinline__ float bf16_hi(unsigned int w) {
    return __uint_as_float(w & 0xFFFF0000u);
}
__device__ __forceinline__ float reflectf(float v) {
    float r = fabsf(v);
    r = fmodf(r, 510.0f);                 // m = 2*(RES-1)
    return (r > 255.0f) ? (510.0f - r) : r;
}
__device__ __forceinline__ unsigned spread3(unsigned v) { // 4-bit -> stride-3
    return (v & 1u) | ((v & 2u) << 2) | ((v & 4u) << 4) | ((v & 8u) << 6);
}
__device__ __forceinline__ int point_cell(const float* __restrict__ coords, int i) {
    const float r0 = reflectf((coords[3 * (size_t)i + 0] + 1.0f) * 127.5f);
    const float r1 = reflectf((coords[3 * (size_t)i + 1] + 1.0f) * 127.5f);
    const float r2 = reflectf((coords[3 * (size_t)i + 2] + 1.0f) * 127.5f);
    const unsigned cx = (unsigned)min(max((int)r0, 0), 255) >> 4;
    const unsigned cy = (unsigned)min(max((int)r1, 0), 255) >> 4;
    const unsigned cz = (unsigned)min(max((int)r2, 0), 255) >> 4;
    return (int)(spread3(cx) | (spread3(cy) << 1) | (spread3(cz) << 2));
}

// ---------------------------------------------------------------------------
// Transpose+pack f32 [3][128][256][256] -> bf16-pair uint32 [3][256][256][64],
// FUSED with Morton-cell histogram.
//
// v4: PLAIN cached loads (NT reverted). Round-0 counters showed FETCH=52MB
// vs 100.7MB logical read: half the persistent f32 input survives in L3
// across iterations (only the workspace is re-poisoned, not inputs). NT
// loads (evict-first) threw that reuse away.
// ---------------------------------------------------------------------------
__global__ __launch_bounds__(256) void fg_transpose_hist(
    const float* __restrict__ in, unsigned int* __restrict__ out,
    const float* __restrict__ coords, unsigned* __restrict__ hist, int n)
{
    __shared__ unsigned int tile[QG / 2][RES + 4];   // packed bf16-pairs, stride 260 words
    const int tid = threadIdx.x;
    const int qg = blockIdx.x;            // 0..3
    const int y  = blockIdx.y;            // 0..255
    const int p  = blockIdx.z;            // 0..2

    // --- histogram slice for this block ---
    {
        const int bid = (p * RES + y) * 4 + qg;          // 0..3071
        const int per = (n + TBLK - 1) / TBLK;           // 86 for n=262144
        const int s0 = bid * per;
        const int s1 = min(s0 + per, n);
        for (int k = s0 + tid; k < s1; k += 256)
            atomicAdd(&hist[point_cell(coords, k)], 1u);
    }

    const int q0 = qg * QG;
    const float* src = in + (((size_t)p * NCH + q0) * RES + y) * RES;
    #pragma unroll
    for (int it = 0; it < 4; ++it) {       // 16 pair-rows x 64 float4-cols
        const int lin = it * 256 + tid;    // 0..1023
        const int k   = lin >> 6;          // pair row within group (0..15)
        const int x4  = lin & 63;          // float4 index within row
        const float4 a = *(const float4*)(src + (size_t)(2 * k + 0) * (RES * RES) + x4 * 4);
        const float4 b = *(const float4*)(src + (size_t)(2 * k + 1) * (RES * RES) + x4 * 4);
        uint4 w;
        w.x = f32_to_bf16_rne(a.x) | (f32_to_bf16_rne(b.x) << 16);
        w.y = f32_to_bf16_rne(a.y) | (f32_to_bf16_rne(b.y) << 16);
        w.z = f32_to_bf16_rne(a.z) | (f32_to_bf16_rne(b.z) << 16);
        w.w = f32_to_bf16_rne(a.w) | (f32_to_bf16_rne(b.w) << 16);
        *(uint4*)&tile[k][x4 * 4] = w;
    }
    __syncthreads();
    unsigned int* dst = out + (((size_t)p * RES + y) * RES) * NPK + (q0 >> 1);
    #pragma unroll
    for (int it = 0; it < 4; ++it) {       // 256 x-cols x 4 uint4-groups
        const int lin = it * 256 + tid;    // 0..1023
        const int q4 = lin & 3;            // uint4 group within the 16 pairs
        const int x  = lin >> 2;           // x column 0..255
        uint4 w;
        w.x = tile[4 * q4 + 0][x];
        w.y = tile[4 * q4 + 1][x];
        w.z = tile[4 * q4 + 2][x];
        w.w = tile[4 * q4 + 3][x];
        *(uint4*)&dst[(size_t)x * NPK + q4 * 4] = w;
    }
}

// ---------------------------------------------------------------------------
// Exclusive scan over 4096 bins (one block, wave-shuffle prefix, 1 barrier)
// + frp precompute
// ---------------------------------------------------------------------------
__global__ __launch_bounds__(256) void fg_scan(
    const unsigned* __restrict__ hist, unsigned* __restrict__ cursor,
    const float* __restrict__ freqs, float* __restrict__ frp)
{
    __shared__ unsigned wtot[4];
    const int t = threadIdx.x;
    const int lane = t & 63;
    const int wid = t >> 6;
    unsigned loc[16];
    unsigned sum = 0;
    #pragma unroll
    for (int k = 0; k < 16; ++k) { loc[k] = hist[t * 16 + k]; sum += loc[k]; }
    // wave-inclusive scan of sum
    unsigned v = sum;
    #pragma unroll
    for (int off = 1; off < 64; off <<= 1) {
        unsigned u = __shfl_up(v, off);
        if (lane >= off) v += u;
    }
    if (lane == 63) wtot[wid] = v;
    __syncthreads();
    unsigned base = 0;
    #pragma unroll
    for (int w = 0; w < 4; ++w) base += (w < wid) ? wtot[w] : 0u;
    unsigned run = base + (v - sum);      // exclusive prefix for this thread
    #pragma unroll
    for (int k = 0; k < 16; ++k) { cursor[t * 16 + k] = run; run += loc[k]; }
    if (t < 128) {
        const float f = fminf(fmaxf(freqs[t], 0.0f), 1.0f);
        frp[t] = __builtin_amdgcn_exp2f(f * 8.0f) - 0.5f;
    }
}

// ---------------------------------------------------------------------------
// Scatter: sort points into Morton order, emitting a 16B RECORD per point:
// {pts0, pts1, pts2, bitcast(original index)}.
// ---------------------------------------------------------------------------
__global__ __launch_bounds__(256) void fg_scatter(
    const float* __restrict__ coords, unsigned* __restrict__ cursor,
    float4* __restrict__ rec, int n)
{
    const int i = blockIdx.x * 256 + threadIdx.x;
    if (i >= n) return;
    const float c0 = coords[3 * (size_t)i + 0];
    const float c1 = coords[3 * (size_t)i + 1];
    const float c2 = coords[3 * (size_t)i + 2];
    const float p0 = (c0 + 1.0f) * 127.5f;
    const float p1 = (c1 + 1.0f) * 127.5f;
    const float p2 = (c2 + 1.0f) * 127.5f;
    const float r0 = reflectf(p0);
    const float r1 = reflectf(p1);
    const float r2 = reflectf(p2);
    const unsigned cx = (unsigned)min(max((int)r0, 0), 255) >> 4;
    const unsigned cy = (unsigned)min(max((int)r1, 0), 255) >> 4;
    const unsigned cz = (unsigned)min(max((int)r2, 0), 255) >> 4;
    const int cell = (int)(spread3(cx) | (spread3(cy) << 1) | (spread3(cz) << 2));
    const unsigned pos = atomicAdd(&cursor[cell], 1u);
    rec[pos] = make_float4(p0, p1, p2, __uint_as_float((unsigned)i));
}

// ---------------------------------------------------------------------------
// Per-point setup + consume helpers for the main kernel (forceinline, all
// indices compile-time after unroll).
// ---------------------------------------------------------------------------
struct PtSetup {
    float A[3], W00[3], W01[3], W10[3], W11[3];
    int   off[3][4];
};

__device__ __forceinline__ void pt_setup(const float4 r, const int c, PtSetup& s) {
    const float pts0 = r.x, pts1 = r.y, pts2 = r.z;
    #pragma unroll
    for (int p = 0; p < 3; ++p) {
        const float sx = (p == 0) ? pts1 : pts0;
        const float sy = (p == 2) ? pts1 : pts2;
        const float pp = (p == 0) ? pts0 : ((p == 1) ? pts1 : pts2);
        const float ix = reflectf(sx);
        const float iy = reflectf(sy);
        const float x0f = floorf(ix), y0f = floorf(iy);
        const float wx = ix - x0f, wy = iy - y0f;
        int x0 = (int)x0f; x0 = min(max(x0, 0), RES - 1);
        int y0 = (int)y0f; y0 = min(max(y0, 0), RES - 1);
        const int x1 = min(x0 + 1, RES - 1);
        const int y1 = min(y0 + 1, RES - 1);
        s.W00[p] = (1.0f - wx) * (1.0f - wy);
        s.W01[p] = wx * (1.0f - wy);
        s.W10[p] = (1.0f - wx) * wy;
        s.W11[p] = wx * wy;
        s.A[p] = (pp + 0.5f) * (1.0f / 512.0f);
        const int rowbase = p * (RES * RES);
        s.off[p][0] = (rowbase + y0 * RES + x0) * NPK + c * 4;
        s.off[p][1] = (rowbase + y0 * RES + x1) * NPK + c * 4;
        s.off[p][2] = (rowbase + y1 * RES + x0) * NPK + c * 4;
        s.off[p][3] = (rowbase + y1 * RES + x1) * NPK + c * 4;
    }
}

__device__ __forceinline__ float pt_consume(const PtSetup& s, const uint4 g[3][4],
                                            const float* __restrict__ frp) {
    float acc = 0.0f;
    #pragma unroll
    for (int p = 0; p < 3; ++p) {
        const unsigned int w0[4] = {g[p][0].x, g[p][0].y, g[p][0].z, g[p][0].w};
        const unsigned int w1[4] = {g[p][1].x, g[p][1].y, g[p][1].z, g[p][1].w};
        const unsigned int w2[4] = {g[p][2].x, g[p][2].y, g[p][2].z, g[p][2].w};
        const unsigned int w3[4] = {g[p][3].x, g[p][3].y, g[p][3].z, g[p][3].w};
        const float w00 = s.W00[p], w01 = s.W01[p], w10 = s.W10[p], w11 = s.W11[p];
        const float A = s.A[p];
        #pragma unroll
        for (int jj = 0; jj < 4; ++jj) {
            const float clo = w00 * bf16_lo(w0[jj]) + w01 * bf16_lo(w1[jj])
                            + w10 * bf16_lo(w2[jj]) + w11 * bf16_lo(w3[jj]);
            const float chi = w00 * bf16_hi(w0[jj]) + w01 * bf16_hi(w1[jj])
                            + w10 * bf16_hi(w2[jj]) + w11 * bf16_hi(w3[jj]);
            const float rl = __builtin_amdgcn_fractf(A * frp[2 * jj + 0]);
            const float rh = __builtin_amdgcn_fractf(A * frp[2 * jj + 1]);
            acc += clo * __builtin_amdgcn_cosf(rl);
            acc += chi * __builtin_amdgcn_cosf(rh);
        }
    }
    return acc;
}

// ---------------------------------------------------------------------------
// Main kernel v4: TWO points per thread (32/block). Issue all 24 gathers
// (12 per point) before consuming either -> 2x memory-level parallelism
// per thread. Named gA/gB staging, compile-time indices only.
// ---------------------------------------------------------------------------
__global__ __launch_bounds__(256) void fg_main_bf16(
    const unsigned int* __restrict__ grid,   // [3][256][256][64]
    const float* __restrict__ frp_in,        // 128 precomputed (fr+0.5)
    const float4* __restrict__ rec,
    float* __restrict__ out, int n)
{
    const int t = threadIdx.x;
    const int c = t & 15;                        // output channel 0..15
    int b = blockIdx.x;
    {
        const int G = gridDim.x;
        const int chunk = G >> 3;
        const int lim = chunk << 3;
        if (b < lim) b = (b & 7) * chunk + (b >> 3);  // undo round-robin
    }
    const int slotA = b * 32 + (t >> 4);         // sorted slots
    const int slotB = slotA + 16;
    if (slotA >= n) return;
    const bool hasB = (slotB < n);

    const float4 rA = rec[slotA];
    const float4 rB = rec[hasB ? slotB : slotA];
    const int iA = (int)__float_as_uint(rA.w);
    const int iB = (int)__float_as_uint(rB.w);

    float frp[8];
    *(float4*)(frp + 0) = *(const float4*)(frp_in + c * 8 + 0);
    *(float4*)(frp + 4) = *(const float4*)(frp_in + c * 8 + 4);

    PtSetup sA, sB;
    pt_setup(rA, c, sA);
    pt_setup(rB, c, sB);

    uint4 gA[3][4], gB[3][4];
    #pragma unroll
    for (int p = 0; p < 3; ++p) {
        #pragma unroll
        for (int q = 0; q < 4; ++q)
            gA[p][q] = *(const uint4*)(grid + sA.off[p][q]);
    }
    #pragma unroll
    for (int p = 0; p < 3; ++p) {
        #pragma unroll
        for (int q = 0; q < 4; ++q)
            gB[p][q] = *(const uint4*)(grid + sB.off[p][q]);
    }

    const float accA = pt_consume(sA, gA, frp);
    __builtin_nontemporal_store(2.0f * accA, &out[(size_t)iA * NC + c]);

    const float accB = pt_consume(sB, gB, frp);
    if (hasB)
        __builtin_nontemporal_store(2.0f * accB, &out[(size_t)iB * NC + c]);
}

// Fallback (no workspace): direct f32 channel-major gather.
__global__ __launch_bounds__(256) void fg_main_f32(
    const float* __restrict__ coords,
    const float* __restrict__ grid,
    const float* __restrict__ freqs,
    float* __restrict__ out, int n)
{
    const int t = threadIdx.x;
    const int c = t & 15;
    const int i = blockIdx.x * 16 + (t >> 4);
    if (i >= n) return;

    float frp[8];
    #pragma unroll
    for (int j = 0; j < 8; ++j) {
        float f = fminf(fmaxf(freqs[c * 8 + j], 0.0f), 1.0f);
        frp[j] = __builtin_amdgcn_exp2f(f * 8.0f) - 0.5f;
    }
    const float c0 = coords[3 * (size_t)i + 0];
    const float c1 = coords[3 * (size_t)i + 1];
    const float c2 = coords[3 * (size_t)i + 2];
    const float pts0 = (c0 + 1.0f) * 127.5f;
    const float pts1 = (c1 + 1.0f) * 127.5f;
    const float pts2 = (c2 + 1.0f) * 127.5f;
    float acc = 0.0f;
    #pragma unroll
    for (int p = 0; p < 3; ++p) {
        const float sx = (p == 0) ? pts1 : pts0;
        const float sy = (p == 2) ? pts1 : pts2;
        const float pp = (p == 0) ? pts0 : ((p == 1) ? pts1 : pts2);
        const float ix = reflectf(sx);
        const float iy = reflectf(sy);
        const float x0f = floorf(ix), y0f = floorf(iy);
        const float wx = ix - x0f, wy = iy - y0f;
        int x0 = (int)x0f; x0 = min(max(x0, 0), RES - 1);
        int y0 = (int)y0f; y0 = min(max(y0, 0), RES - 1);
        const int x1 = min(x0 + 1, RES - 1);
        const int y1 = min(y0 + 1, RES - 1);
        const float w00 = (1.0f - wx) * (1.0f - wy);
        const float w01 = wx * (1.0f - wy);
        const float w10 = (1.0f - wx) * wy;
        const float w11 = wx * wy;
        const float A = (pp + 0.5f) * (1.0f / 512.0f);
        const size_t plane = (size_t)p * NCH * RES * RES;
        const int o00 = y0 * RES + x0, o01 = y0 * RES + x1;
        const int o10 = y1 * RES + x0, o11 = y1 * RES + x1;
        #pragma unroll
        for (int j = 0; j < 8; ++j) {
            const float* gq = grid + plane + (size_t)(c * 8 + j) * (RES * RES);
            const float coef = w00 * gq[o00] + w01 * gq[o01]
                             + w10 * gq[o10] + w11 * gq[o11];
            const float rr = __builtin_amdgcn_fractf(A * frp[j]);
            acc += coef * __builtin_amdgcn_cosf(rr);
        }
    }
    out[(size_t)i * NC + c] = 2.0f * acc;
}

extern "C" void kernel_launch(void* const* d_in, const int* in_sizes, int n_in,
                              void* d_out, int out_size, void* d_ws, size_t ws_size,
                              hipStream_t stream)
{
    const float* coords = (const float*)d_in[0];
    const float* grid   = (const float*)d_in[1];
    const float* freqs  = (const float*)d_in[2];
    float* out = (float*)d_out;
    const int n = in_sizes[0] / 3;

    // Workspace layout (all 16B-aligned)
    const size_t gridT_b  = (size_t)3 * RES * RES * NPK * sizeof(unsigned); // 50.33 MB
    const size_t hist_b   = (size_t)NBINS * sizeof(unsigned);
    const size_t frp_b    = 128 * sizeof(float);
    const size_t rec_b    = (size_t)n * sizeof(float4);
    const size_t need = gridT_b + 2 * hist_b + frp_b + rec_b;

    if (ws_size >= need) {
        char* ws = (char*)d_ws;
        unsigned* gridT  = (unsigned*)ws;                 ws += gridT_b;
        unsigned* hist   = (unsigned*)ws;                 ws += hist_b;
        unsigned* cursor = (unsigned*)ws;                 ws += hist_b;
        float*    frp    = (float*)ws;                    ws += frp_b;
        float4*   rec    = (float4*)ws;

        (void)hipMemsetAsync(hist, 0, hist_b, stream);
        hipLaunchKernelGGL(fg_transpose_hist, dim3(4, RES, 3), dim3(256), 0, stream,
                           grid, gridT, coords, hist, n);
        hipLaunchKernelGGL(fg_scan, dim3(1), dim3(256), 0, stream,
                           hist, cursor, freqs, frp);
        hipLaunchKernelGGL(fg_scatter, dim3((n + 255) / 256), dim3(256), 0, stream,
                           coords, cursor, rec, n);
        const int blocks2 = (n + 31) / 32;
        hipLaunchKernelGGL(fg_main_bf16, dim3(blocks2), dim3(256), 0, stream,
                           gridT, frp, rec, out, n);
    } else {
        const int blocks = (n + 15) / 16;
        hipLaunchKernelGGL(fg_main_f32, dim3(blocks), dim3(256), 0, stream,
                           coords, grid, freqs, out, n);
    }
}

// Round 5
// 243.995 us; speedup vs baseline: 1.0113x; 1.0113x over previous
//
#include <hip/hip_runtime.h>

#define RES   256
#define NCH   128   // C*F
#define NC    16
#define QG    32    // channels per transpose block
#define NPK   64    // packed uint32 per (p,y,x) position = NCH/2
#define NBINS 4096  // 16^3 Morton cells
#define TBLK  3072  // transpose grid size (4*256*3)

typedef float fx2 __attribute__((ext_vector_type(2)));  // bait v_pk_*_f32

__device__ __forceinline__ unsigned int f32_to_bf16_rne(float f) {
    unsigned int u = __float_as_uint(f);
    return (u + 0x7FFFu + ((u >> 16) & 1u)) >> 16;
}
__device__ __forceinline__ float bf16_lo(unsigned int w) {
    return __uint_as_float(w << 16);
}
__device__ __forceinline__ float bf16_hi(unsigned int w) {
    return __uint_as_float(w & 0xFFFF0000u);
}
__device__ __forceinline__ float reflectf(float v) {
    float r = fabsf(v);
    r = fmodf(r, 510.0f);                 // m = 2*(RES-1)
    return (r > 255.0f) ? (510.0f - r) : r;
}
__device__ __forceinline__ unsigned spread3(unsigned v) { // 4-bit -> stride-3
    return (v & 1u) | ((v & 2u) << 2) | ((v & 4u) << 4) | ((v & 8u) << 6);
}
__device__ __forceinline__ int point_cell(const float* __restrict__ coords, int i) {
    const float r0 = reflectf((coords[3 * (size_t)i + 0] + 1.0f) * 127.5f);
    const float r1 = reflectf((coords[3 * (size_t)i + 1] + 1.0f) * 127.5f);
    const float r2 = reflectf((coords[3 * (size_t)i + 2] + 1.0f) * 127.5f);
    const unsigned cx = (unsigned)min(max((int)r0, 0), 255) >> 4;
    const unsigned cy = (unsigned)min(max((int)r1, 0), 255) >> 4;
    const unsigned cz = (unsigned)min(max((int)r2, 0), 255) >> 4;
    return (int)(spread3(cx) | (spread3(cy) << 1) | (spread3(cz) << 2));
}

// ---------------------------------------------------------------------------
// Transpose+pack f32 [3][128][256][256] -> bf16-pair uint32 [3][256][256][64],
// FUSED with Morton-cell histogram. (v4 form: plain cached loads; L3 keeps
// ~half the persistent f32 input warm across iterations.)
// ---------------------------------------------------------------------------
__global__ __launch_bounds__(256) void fg_transpose_hist(
    const float* __restrict__ in, unsigned int* __restrict__ out,
    const float* __restrict__ coords, unsigned* __restrict__ hist, int n)
{
    __shared__ unsigned int tile[QG / 2][RES + 4];   // packed bf16-pairs, stride 260 words
    const int tid = threadIdx.x;
    const int qg = blockIdx.x;            // 0..3
    const int y  = blockIdx.y;            // 0..255
    const int p  = blockIdx.z;            // 0..2

    // --- histogram slice for this block ---
    {
        const int bid = (p * RES + y) * 4 + qg;          // 0..3071
        const int per = (n + TBLK - 1) / TBLK;           // 86 for n=262144
        const int s0 = bid * per;
        const int s1 = min(s0 + per, n);
        for (int k = s0 + tid; k < s1; k += 256)
            atomicAdd(&hist[point_cell(coords, k)], 1u);
    }

    const int q0 = qg * QG;
    const float* src = in + (((size_t)p * NCH + q0) * RES + y) * RES;
    #pragma unroll
    for (int it = 0; it < 4; ++it) {       // 16 pair-rows x 64 float4-cols
        const int lin = it * 256 + tid;    // 0..1023
        const int k   = lin >> 6;          // pair row within group (0..15)
        const int x4  = lin & 63;          // float4 index within row
        const float4 a = *(const float4*)(src + (size_t)(2 * k + 0) * (RES * RES) + x4 * 4);
        const float4 b = *(const float4*)(src + (size_t)(2 * k + 1) * (RES * RES) + x4 * 4);
        uint4 w;
        w.x = f32_to_bf16_rne(a.x) | (f32_to_bf16_rne(b.x) << 16);
        w.y = f32_to_bf16_rne(a.y) | (f32_to_bf16_rne(b.y) << 16);
        w.z = f32_to_bf16_rne(a.z) | (f32_to_bf16_rne(b.z) << 16);
        w.w = f32_to_bf16_rne(a.w) | (f32_to_bf16_rne(b.w) << 16);
        *(uint4*)&tile[k][x4 * 4] = w;
    }
    __syncthreads();
    unsigned int* dst = out + (((size_t)p * RES + y) * RES) * NPK + (q0 >> 1);
    #pragma unroll
    for (int it = 0; it < 4; ++it) {       // 256 x-cols x 4 uint4-groups
        const int lin = it * 256 + tid;    // 0..1023
        const int q4 = lin & 3;            // uint4 group within the 16 pairs
        const int x  = lin >> 2;           // x column 0..255
        uint4 w;
        w.x = tile[4 * q4 + 0][x];
        w.y = tile[4 * q4 + 1][x];
        w.z = tile[4 * q4 + 2][x];
        w.w = tile[4 * q4 + 3][x];
        *(uint4*)&dst[(size_t)x * NPK + q4 * 4] = w;
    }
}

// ---------------------------------------------------------------------------
// Exclusive scan over 4096 bins + frp precompute
// ---------------------------------------------------------------------------
__global__ __launch_bounds__(256) void fg_scan(
    const unsigned* __restrict__ hist, unsigned* __restrict__ cursor,
    const float* __restrict__ freqs, float* __restrict__ frp)
{
    __shared__ unsigned wtot[4];
    const int t = threadIdx.x;
    const int lane = t & 63;
    const int wid = t >> 6;
    unsigned loc[16];
    unsigned sum = 0;
    #pragma unroll
    for (int k = 0; k < 16; ++k) { loc[k] = hist[t * 16 + k]; sum += loc[k]; }
    unsigned v = sum;
    #pragma unroll
    for (int off = 1; off < 64; off <<= 1) {
        unsigned u = __shfl_up(v, off);
        if (lane >= off) v += u;
    }
    if (lane == 63) wtot[wid] = v;
    __syncthreads();
    unsigned base = 0;
    #pragma unroll
    for (int w = 0; w < 4; ++w) base += (w < wid) ? wtot[w] : 0u;
    unsigned run = base + (v - sum);      // exclusive prefix for this thread
    #pragma unroll
    for (int k = 0; k < 16; ++k) { cursor[t * 16 + k] = run; run += loc[k]; }
    if (t < 128) {
        const float f = fminf(fmaxf(freqs[t], 0.0f), 1.0f);
        frp[t] = __builtin_amdgcn_exp2f(f * 8.0f) - 0.5f;
    }
}

// ---------------------------------------------------------------------------
// Scatter v5: Morton-sort AND hoist ALL per-point setup here (computed once
// per point instead of 16x in main). Per point emits:
//   recP[pos*3+p] = {A_p, wx_p, wy_p, bitcast(o00 | edge flags)}   (48 B)
//   idx[pos]      = original index                                  (4 B)
// o00 = (p*65536 + y0*256 + x0)*64 fits in 24 bits; bit24 = x0<255 (dx=64
// valid), bit25 = y0<255 (dy=16384 valid).
// ---------------------------------------------------------------------------
__global__ __launch_bounds__(256) void fg_scatter(
    const float* __restrict__ coords, unsigned* __restrict__ cursor,
    float4* __restrict__ recP, unsigned* __restrict__ idx, int n)
{
    const int i = blockIdx.x * 256 + threadIdx.x;
    if (i >= n) return;
    const float c0 = coords[3 * (size_t)i + 0];
    const float c1 = coords[3 * (size_t)i + 1];
    const float c2 = coords[3 * (size_t)i + 2];
    const float p0 = (c0 + 1.0f) * 127.5f;
    const float p1 = (c1 + 1.0f) * 127.5f;
    const float p2 = (c2 + 1.0f) * 127.5f;
    const float r0 = reflectf(p0);
    const float r1 = reflectf(p1);
    const float r2 = reflectf(p2);
    const unsigned cx = (unsigned)min(max((int)r0, 0), 255) >> 4;
    const unsigned cy = (unsigned)min(max((int)r1, 0), 255) >> 4;
    const unsigned cz = (unsigned)min(max((int)r2, 0), 255) >> 4;
    const int cell = (int)(spread3(cx) | (spread3(cy) << 1) | (spread3(cz) << 2));
    const unsigned pos = atomicAdd(&cursor[cell], 1u);

    #pragma unroll
    for (int p = 0; p < 3; ++p) {
        const float ix = (p == 0) ? r1 : r0;
        const float iy = (p == 2) ? r1 : r2;
        const float pp = (p == 0) ? p0 : ((p == 1) ? p1 : p2);
        const float x0f = floorf(ix), y0f = floorf(iy);
        const float wx = ix - x0f, wy = iy - y0f;
        const int x0 = min(max((int)x0f, 0), RES - 1);
        const int y0 = min(max((int)y0f, 0), RES - 1);
        unsigned ob = (unsigned)(((p << 16) | (y0 << 8) | x0) << 6);
        if (x0 < RES - 1) ob |= (1u << 24);
        if (y0 < RES - 1) ob |= (1u << 25);
        const float A = (pp + 0.5f) * (1.0f / 512.0f);
        recP[(size_t)pos * 3 + p] = make_float4(A, wx, wy, __uint_as_float(ob));
    }
    idx[pos] = (unsigned)i;
}

// ---------------------------------------------------------------------------
// Main kernel v5: 1 point per thread (16 lanes/point, one channel each).
//  - setup precomputed in scatter: per plane just 6 ops for weights and
//    ~8 ops for the 4 offsets (base & 0xFFFFFF, dx/dy from flag bits)
//  - all 12 gathers issued before consumption
//  - interp/phase/accumulate written as native float2 (fx2) to bait
//    v_pk_fma_f32 / v_pk_mul_f32 packed issue
// ---------------------------------------------------------------------------
__global__ __launch_bounds__(256) void fg_main_bf16(
    const unsigned int* __restrict__ grid,   // [3][256][256][64]
    const float* __restrict__ frp_in,        // 128 precomputed (fr+0.5)
    const float4* __restrict__ recP,
    const unsigned* __restrict__ idx,
    float* __restrict__ out, int n)
{
    const int t = threadIdx.x;
    const int c = t & 15;                        // output channel 0..15
    int b = blockIdx.x;
    {
        const int G = gridDim.x;
        const int chunk = G >> 3;
        const int lim = chunk << 3;
        if (b < lim) b = (b & 7) * chunk + (b >> 3);  // undo round-robin
    }
    const int slot = b * 16 + (t >> 4);          // sorted slot
    if (slot >= n) return;

    float4 P[3];
    P[0] = recP[(size_t)slot * 3 + 0];
    P[1] = recP[(size_t)slot * 3 + 1];
    P[2] = recP[(size_t)slot * 3 + 2];
    const unsigned i = idx[slot];

    fx2 frpv[4];
    {
        float frp[8];
        *(float4*)(frp + 0) = *(const float4*)(frp_in + c * 8 + 0);
        *(float4*)(frp + 4) = *(const float4*)(frp_in + c * 8 + 4);
        #pragma unroll
        for (int jj = 0; jj < 4; ++jj) {
            frpv[jj].x = frp[2 * jj + 0];
            frpv[jj].y = frp[2 * jj + 1];
        }
    }

    const int c4 = c * 4;
    uint4 g[3][4];
    #pragma unroll
    for (int p = 0; p < 3; ++p) {
        const unsigned bits = __float_as_uint(P[p].w);
        const int base = (int)(bits & 0x00FFFFFFu) + c4;
        const int dx = (int)((bits >> 18) & 64u);      // bit24 -> 64
        const int dy = (int)((bits >> 11) & 16384u);   // bit25 -> 16384
        g[p][0] = *(const uint4*)(grid + base);
        g[p][1] = *(const uint4*)(grid + base + dx);
        g[p][2] = *(const uint4*)(grid + base + dy);
        g[p][3] = *(const uint4*)(grid + base + dx + dy);
    }

    fx2 acc2 = {0.0f, 0.0f};
    #pragma unroll
    for (int p = 0; p < 3; ++p) {
        const float wx = P[p].y, wy = P[p].z;
        const float u = 1.0f - wx, v = 1.0f - wy;
        const float w00 = u * v,  w01 = wx * v;
        const float w10 = u * wy, w11 = wx * wy;
        const float A = P[p].x;
        const unsigned int w0[4] = {g[p][0].x, g[p][0].y, g[p][0].z, g[p][0].w};
        const unsigned int w1[4] = {g[p][1].x, g[p][1].y, g[p][1].z, g[p][1].w};
        const unsigned int w2[4] = {g[p][2].x, g[p][2].y, g[p][2].z, g[p][2].w};
        const unsigned int w3[4] = {g[p][3].x, g[p][3].y, g[p][3].z, g[p][3].w};

        #pragma unroll
        for (int jj = 0; jj < 4; ++jj) {
            fx2 v0; v0.x = bf16_lo(w0[jj]); v0.y = bf16_hi(w0[jj]);
            fx2 v1; v1.x = bf16_lo(w1[jj]); v1.y = bf16_hi(w1[jj]);
            fx2 v2; v2.x = bf16_lo(w2[jj]); v2.y = bf16_hi(w2[jj]);
            fx2 v3; v3.x = bf16_lo(w3[jj]); v3.y = bf16_hi(w3[jj]);
            const fx2 cf = w00 * v0 + w01 * v1 + w10 * v2 + w11 * v3;
            fx2 ph = A * frpv[jj];
            ph.x = __builtin_amdgcn_fractf(ph.x);
            ph.y = __builtin_amdgcn_fractf(ph.y);
            fx2 cs;
            cs.x = __builtin_amdgcn_cosf(ph.x);
            cs.y = __builtin_amdgcn_cosf(ph.y);
            acc2 += cf * cs;
        }
    }

    __builtin_nontemporal_store(2.0f * (acc2.x + acc2.y), &out[(size_t)i * NC + c]);
}

// Fallback (no workspace): direct f32 channel-major gather.
__global__ __launch_bounds__(256) void fg_main_f32(
    const float* __restrict__ coords,
    const float* __restrict__ grid,
    const float* __restrict__ freqs,
    float* __restrict__ out, int n)
{
    const int t = threadIdx.x;
    const int c = t & 15;
    const int i = blockIdx.x * 16 + (t >> 4);
    if (i >= n) return;

    float frp[8];
    #pragma unroll
    for (int j = 0; j < 8; ++j) {
        float f = fminf(fmaxf(freqs[c * 8 + j], 0.0f), 1.0f);
        frp[j] = __builtin_amdgcn_exp2f(f * 8.0f) - 0.5f;
    }
    const float c0 = coords[3 * (size_t)i + 0];
    const float c1 = coords[3 * (size_t)i + 1];
    const float c2 = coords[3 * (size_t)i + 2];
    const float pts0 = (c0 + 1.0f) * 127.5f;
    const float pts1 = (c1 + 1.0f) * 127.5f;
    const float pts2 = (c2 + 1.0f) * 127.5f;
    float acc = 0.0f;
    #pragma unroll
    for (int p = 0; p < 3; ++p) {
        const float sx = (p == 0) ? pts1 : pts0;
        const float sy = (p == 2) ? pts1 : pts2;
        const float pp = (p == 0) ? pts0 : ((p == 1) ? pts1 : pts2);
        const float ix = reflectf(sx);
        const float iy = reflectf(sy);
        const float x0f = floorf(ix), y0f = floorf(iy);
        const float wx = ix - x0f, wy = iy - y0f;
        int x0 = (int)x0f; x0 = min(max(x0, 0), RES - 1);
        int y0 = (int)y0f; y0 = min(max(y0, 0), RES - 1);
        const int x1 = min(x0 + 1, RES - 1);
        const int y1 = min(y0 + 1, RES - 1);
        const float w00 = (1.0f - wx) * (1.0f - wy);
        const float w01 = wx * (1.0f - wy);
        const float w10 = (1.0f - wx) * wy;
        const float w11 = wx * wy;
        const float A = (pp + 0.5f) * (1.0f / 512.0f);
        const size_t plane = (size_t)p * NCH * RES * RES;
        const int o00 = y0 * RES + x0, o01 = y0 * RES + x1;
        const int o10 = y1 * RES + x0, o11 = y1 * RES + x1;
        #pragma unroll
        for (int j = 0; j < 8; ++j) {
            const float* gq = grid + plane + (size_t)(c * 8 + j) * (RES * RES);
            const float coef = w00 * gq[o00] + w01 * gq[o01]
                             + w10 * gq[o10] + w11 * gq[o11];
            const float rr = __builtin_amdgcn_fractf(A * frp[j]);
            acc += coef * __builtin_amdgcn_cosf(rr);
        }
    }
    out[(size_t)i * NC + c] = 2.0f * acc;
}

extern "C" void kernel_launch(void* const* d_in, const int* in_sizes, int n_in,
                              void* d_out, int out_size, void* d_ws, size_t ws_size,
                              hipStream_t stream)
{
    const float* coords = (const float*)d_in[0];
    const float* grid   = (const float*)d_in[1];
    const float* freqs  = (const float*)d_in[2];
    float* out = (float*)d_out;
    const int n = in_sizes[0] / 3;

    // Workspace layout (all 16B-aligned)
    const size_t gridT_b  = (size_t)3 * RES * RES * NPK * sizeof(unsigned); // 50.33 MB
    const size_t hist_b   = (size_t)NBINS * sizeof(unsigned);
    const size_t frp_b    = 128 * sizeof(float);
    const size_t recP_b   = (size_t)n * 3 * sizeof(float4);                 // 12.6 MB
    const size_t idx_b    = (size_t)((n + 3) & ~3) * sizeof(unsigned);
    const size_t need = gridT_b + 2 * hist_b + frp_b + recP_b + idx_b;

    if (ws_size >= need) {
        char* ws = (char*)d_ws;
        unsigned* gridT  = (unsigned*)ws;                 ws += gridT_b;
        unsigned* hist   = (unsigned*)ws;                 ws += hist_b;
        unsigned* cursor = (unsigned*)ws;                 ws += hist_b;
        float*    frp    = (float*)ws;                    ws += frp_b;
        float4*   recP   = (float4*)ws;                   ws += recP_b;
        unsigned* idxb   = (unsigned*)ws;

        (void)hipMemsetAsync(hist, 0, hist_b, stream);
        hipLaunchKernelGGL(fg_transpose_hist, dim3(4, RES, 3), dim3(256), 0, stream,
                           grid, gridT, coords, hist, n);
        hipLaunchKernelGGL(fg_scan, dim3(1), dim3(256), 0, stream,
                           hist, cursor, freqs, frp);
        hipLaunchKernelGGL(fg_scatter, dim3((n + 255) / 256), dim3(256), 0, stream,
                           coords, cursor, recP, idxb, n);
        const int blocks = (n + 15) / 16;
        hipLaunchKernelGGL(fg_main_bf16, dim3(blocks), dim3(256), 0, stream,
                           gridT, frp, recP, idxb, out, n);
    } else {
        const int blocks = (n + 15) / 16;
        hipLaunchKernelGGL(fg_main_f32, dim3(blocks), dim3(256), 0, stream,
                           coords, grid, freqs, out, n);
    }
}